// Round 3
// baseline (7994.948 us; speedup 1.0000x reference)
//
#include <hip/hip_runtime.h>
#include <cstdint>
#include <cstddef>

// ---------------------------------------------------------------------------
// LSTM  B=64, T=1024, D=H=512.
//   * xcvt: x_seq fp32 -> fp16 in ws (one-time).
//   * lstm_rec: persistent, 256 WGs = 8 batch-groups x 32 column-groups.
//     Wh & Wx slices LDS-resident fp16 (140 KB, 1 WG/CU).
//     Tagged h (tag<<16 | fp16), double-buffered; whole-WG cooperative
//     spin-load IS the data load.
//   R6 (this round): INTRA-XCD L2 EXCHANGE.
//     rocprof showed ~12.5k cyc/step with ~175 MB of h-traffic served from
//     HBM: the agent-scope publish/poll path round-trips L3/HBM (~900cyc)
//     several times per step. Fix: batch-group <- physical XCD.
//       * g = HW_REG_XCC_ID (runtime-measured, not dispatch-assumed);
//         c = atomicAdd slot within XCD. 1 WG/CU x 256 WGs => exactly 32
//         WGs per XCD by pigeonhole, so all peers of group g share one L2.
//       * publish: global_store_dwordx2 sc0 (L1-bypass, L2-cached);
//         poll: global_load_dwordx2 sc0 -> L2 hits, ~200-300 cyc.
//       * cross-run stale-L2 tags killed by per-WG sc0 cleanse of its slice
//         (buffer0 <- tag0/payload0 == h_0, buffer1 <- tag 0xFFFF).
//       * belt-and-braces: agent-scope mirror buffer; poll falls back to it
//         every 16 misses => no deadlock even if sc0 semantics are wrong.
// ---------------------------------------------------------------------------

typedef _Float16 half8  __attribute__((ext_vector_type(8)));
typedef _Float16 half4v __attribute__((ext_vector_type(4)));
typedef float    float4v __attribute__((ext_vector_type(4)));

__device__ __forceinline__ float sigm(float x) { return 1.f / (1.f + __expf(-x)); }
__device__ __forceinline__ float tanh_f(float x) { return 2.f / (1.f + __expf(-2.f * x)) - 1.f; }

// 8 x u64 tagged loads, L1-bypass / L2-cached (sc0), one vmcnt drain.
__device__ __forceinline__ void load8_sc0(const unsigned long long* p,
                                          unsigned long long q[8]) {
    asm volatile(
        "global_load_dwordx2 %0, %8, off sc0\n\t"
        "global_load_dwordx2 %1, %8, off offset:8 sc0\n\t"
        "global_load_dwordx2 %2, %8, off offset:16 sc0\n\t"
        "global_load_dwordx2 %3, %8, off offset:24 sc0\n\t"
        "global_load_dwordx2 %4, %8, off offset:32 sc0\n\t"
        "global_load_dwordx2 %5, %8, off offset:40 sc0\n\t"
        "global_load_dwordx2 %6, %8, off offset:48 sc0\n\t"
        "global_load_dwordx2 %7, %8, off offset:56 sc0\n\t"
        "s_waitcnt vmcnt(0)"
        : "=&v"(q[0]), "=&v"(q[1]), "=&v"(q[2]), "=&v"(q[3]),
          "=&v"(q[4]), "=&v"(q[5]), "=&v"(q[6]), "=&v"(q[7])
        : "v"(p)
        : "memory");
}

// ----------------------------- x fp32 -> fp16 ------------------------------
__global__ __launch_bounds__(256) void xcvt(const float* __restrict__ X,
                                            _Float16* __restrict__ XH) {
    size_t i = ((size_t)blockIdx.x * 256 + threadIdx.x) * 8;
    float4 a = *(const float4*)(X + i);
    float4 b = *(const float4*)(X + i + 4);
    half8 v;
    v[0] = (_Float16)a.x; v[1] = (_Float16)a.y; v[2] = (_Float16)a.z; v[3] = (_Float16)a.w;
    v[4] = (_Float16)b.x; v[5] = (_Float16)b.y; v[6] = (_Float16)b.z; v[7] = (_Float16)b.w;
    *(half8*)(XH + i) = v;
}

// ------------------------------- recurrence --------------------------------
__global__ __launch_bounds__(256, 1) void lstm_rec(
    const float* __restrict__ Whf, const float* __restrict__ Whi,
    const float* __restrict__ Whg, const float* __restrict__ Who,
    const float* __restrict__ Wxf, const float* __restrict__ Wxi,
    const float* __restrict__ Wxg, const float* __restrict__ Wxo,
    const float* __restrict__ bxf, const float* __restrict__ bxi,
    const float* __restrict__ bxg, const float* __restrict__ bxo,
    const float* __restrict__ bhf, const float* __restrict__ bhi,
    const float* __restrict__ bhg, const float* __restrict__ bho,
    const _Float16* __restrict__ XH,        // [64][1024][512] fp16
    unsigned long long* __restrict__ hws,   // [0,256K) fast h | +32B ctrs | [512K,768K) safe h
    float* __restrict__ out)                // [64][512] fp32
{
    const int tid  = threadIdx.x;
    const int w    = tid >> 6;
    const int lane = tid & 63;
    const int l15  = lane & 15;
    const int quad = lane >> 4;
    const int m    = l15 & 7;

    __shared__ _Float16 Wls[64][520];
    __shared__ _Float16 Xls[64][520];
    __shared__ _Float16 hls[8][520];
    __shared__ float    gs[8][65];
    __shared__ unsigned slot_sh;

    // ---- runtime XCD self-organization: g = physical XCD, c = slot ----
    unsigned xcd;
    asm volatile("s_getreg_b32 %0, hwreg(HW_REG_XCC_ID)" : "=s"(xcd));
    xcd &= 7;
    if (tid == 0) {
        unsigned* ctr = (unsigned*)(hws + 32768);  // byte offset 256K
        slot_sh = __hip_atomic_fetch_add(&ctr[xcd], 1u, __ATOMIC_RELAXED,
                                         __HIP_MEMORY_SCOPE_AGENT);
    }
    __syncthreads();
    const int g = (int)xcd;          // batch group == XCD
    const int c = (int)slot_sh;      // column group 0..31 within XCD

    // ---- one-time: weight slices -> LDS fp16 ----
    const float* WhSeg[4] = {Whf, Whi, Whg, Who};
    const float* WxSeg[4] = {Wxf, Wxi, Wxg, Wxo};
    for (int e = tid * 4; e < 64 * 512; e += 1024) {
        int row = e >> 9, col = e & 511;
        int seg = row >> 4;
        int srow = c * 16 + (row & 15);
        float4 vh = *(const float4*)(WhSeg[seg] + (size_t)srow * 512 + col);
        float4 vx = *(const float4*)(WxSeg[seg] + (size_t)srow * 512 + col);
        half4v th = {(_Float16)vh.x, (_Float16)vh.y, (_Float16)vh.z, (_Float16)vh.w};
        half4v tx = {(_Float16)vx.x, (_Float16)vx.y, (_Float16)vx.z, (_Float16)vx.w};
        *(half4v*)&Wls[row][col] = th;
        *(half4v*)&Xls[row][col] = tx;
    }

    // ---- elementwise role (wave 0): biases + fast-buffer cleanse ----
    const int erow = tid >> 3;
    const int ep   = tid & 7;
    float bs[8] = {0.f};
    if (tid < 64) {
        int u0 = c * 16 + 2 * ep, u1 = u0 + 1;
        bs[0] = bxf[u0] + bhf[u0];  bs[4] = bxf[u1] + bhf[u1];
        bs[1] = bxi[u0] + bhi[u0];  bs[5] = bxi[u1] + bhi[u1];
        bs[2] = bxg[u0] + bhg[u0];  bs[6] = bxg[u1] + bhg[u1];
        bs[3] = bxo[u0] + bho[u0];  bs[7] = bxo[u1] + bho[u1];
        // cleanse own slice through the sc0 path: buffer0 = tag0|h0=0 (the
        // step-0 publish), buffer1 = invalid tag. Overwrites any stale L2
        // lines from a previous run before peers can observe matching tags.
        unsigned long long* f0 = hws + (size_t)g * 2048 + erow * 256 + c * 8 + ep;
        unsigned long long* f1 = f0 + 16384;
        unsigned long long z0 = 0ULL, z1 = 0xFFFF0000FFFF0000ULL;
        asm volatile(
            "global_store_dwordx2 %0, %2, off sc0\n\t"
            "global_store_dwordx2 %1, %3, off sc0"
            :: "v"(f0), "v"(f1), "v"(z0), "v"(z1) : "memory");
    }
    float c0s = 0.f, c1s = 0.f;

    const int crow = tid >> 5;
    const int ccol = (tid & 31) << 4;

    __syncthreads();

    // ---- x-projection shadow: acc_x for step 0 ----
    const size_t xrow = (size_t)(g * 8 + m) * 1024 * 512 + (size_t)quad * 8;
    half8 xf[16];
#pragma unroll
    for (int kk = 0; kk < 16; kk++) xf[kk] = *(const half8*)(XH + xrow + kk * 32);
    float4v accx = {0.f, 0.f, 0.f, 0.f};
#pragma unroll
    for (int kk = 0; kk < 16; kk++) {
        half8 b = *(const half8*)&Xls[w * 16 + l15][kk * 32 + quad * 8];
        accx = __builtin_amdgcn_mfma_f32_16x16x32_f16(xf[kk], b, accx, 0, 0, 0);
    }

    for (int t = 0; t < 1024; t++) {
        // ---- cooperative tagged spin-load of h_t -> LDS (L2 fast path) ----
        {
            const size_t off = (size_t)(t & 1) * 16384 + (size_t)g * 2048
                             + (size_t)tid * 8;
            const unsigned long long* hsrc = hws + off;
            const unsigned long long* ssrc = hws + 65536 + off;  // agent mirror
            const unsigned long long T =
                ((unsigned long long)(unsigned)t << 16) |
                ((unsigned long long)(unsigned)t << 48);
            unsigned long long q[8];
            int miss = 0;
            for (;;) {
                load8_sc0(hsrc, q);
                unsigned long long bad = 0;
#pragma unroll
                for (int j = 0; j < 8; j++)
                    bad |= (q[j] ^ T) & 0xFFFF0000FFFF0000ULL;
                if (!bad) break;
                if (((++miss) & 15) == 0) {   // safety net: agent-scope mirror
                    bad = 0;
#pragma unroll
                    for (int j = 0; j < 8; j++)
                        q[j] = __hip_atomic_load(ssrc + j, __ATOMIC_RELAXED,
                                                 __HIP_MEMORY_SCOPE_AGENT);
#pragma unroll
                    for (int j = 0; j < 8; j++)
                        bad |= (q[j] ^ T) & 0xFFFF0000FFFF0000ULL;
                    if (!bad) break;
                }
            }
            unsigned int* hd = (unsigned int*)&hls[crow][ccol];
#pragma unroll
            for (int j = 0; j < 8; j++)
                hd[j] = (unsigned int)(q[j] & 0xFFFF) |
                        (((unsigned int)(q[j] >> 32)) << 16);
        }

        // ---- issue x loads for t+1; ride across the raw barriers ----
        {
            int tn = (t < 1023) ? (t + 1) : 0;
            const _Float16* xp = XH + xrow + (size_t)tn * 512;
#pragma unroll
            for (int kk = 0; kk < 16; kk++) xf[kk] = *(const half8*)(xp + kk * 32);
        }

        // barrier 1: hls staged (ds ops drained; vmcnt NOT drained)
        asm volatile("s_waitcnt lgkmcnt(0)" ::: "memory");
        __builtin_amdgcn_s_barrier();
        __builtin_amdgcn_sched_barrier(0);

        // ---- h-GEMM: acc = acc_x + h_t @ Wh_slice^T ----
        float4v acca = accx;
        float4v accb = {0.f, 0.f, 0.f, 0.f};
#pragma unroll
        for (int kk = 0; kk < 16; kk += 2) {
            half8 a0 = *(const half8*)&hls[m][kk * 32 + quad * 8];
            half8 a1 = *(const half8*)&hls[m][(kk + 1) * 32 + quad * 8];
            half8 b0 = *(const half8*)&Wls[w * 16 + l15][kk * 32 + quad * 8];
            half8 b1 = *(const half8*)&Wls[w * 16 + l15][(kk + 1) * 32 + quad * 8];
            acca = __builtin_amdgcn_mfma_f32_16x16x32_f16(a0, b0, acca, 0, 0, 0);
            accb = __builtin_amdgcn_mfma_f32_16x16x32_f16(a1, b1, accb, 0, 0, 0);
        }

        if (quad < 2) {
#pragma unroll
            for (int r = 0; r < 4; r++)
                gs[quad * 4 + r][w * 16 + l15] = acca[r] + accb[r];
        }
        // barrier 2: gs ready
        asm volatile("s_waitcnt lgkmcnt(0)" ::: "memory");
        __builtin_amdgcn_s_barrier();
        __builtin_amdgcn_sched_barrier(0);

        // ---- elementwise LSTM update + tagged publish (wave 0 only) ----
        if (tid < 64) {
            float pf0 = gs[erow][2 * ep]      + bs[0];
            float pi0 = gs[erow][2 * ep + 16] + bs[1];
            float pg0 = gs[erow][2 * ep + 32] + bs[2];
            float po0 = gs[erow][2 * ep + 48] + bs[3];
            float pf1 = gs[erow][2 * ep + 1]  + bs[4];
            float pi1 = gs[erow][2 * ep + 17] + bs[5];
            float pg1 = gs[erow][2 * ep + 33] + bs[6];
            float po1 = gs[erow][2 * ep + 49] + bs[7];
            c0s = sigm(pf0) * c0s + sigm(pi0) * tanh_f(pg0);
            c1s = sigm(pf1) * c1s + sigm(pi1) * tanh_f(pg1);
            float hn0 = sigm(po0) * tanh_f(c0s);
            float hn1 = sigm(po1) * tanh_f(c1s);
            union { _Float16 f; unsigned short u; } cv0, cv1;
            cv0.f = (_Float16)hn0; cv1.f = (_Float16)hn1;
            unsigned int tag = (unsigned)(t + 1) << 16;
            unsigned long long qv = (unsigned long long)(tag | cv0.u)
                                  | ((unsigned long long)(tag | cv1.u) << 32);
            size_t poff = (size_t)((t + 1) & 1) * 16384 + (size_t)g * 2048
                        + (size_t)erow * 256 + c * 8 + ep;
            unsigned long long* hd = hws + poff;
            // fast publish: sc0 store -> XCD-local L2 (peers poll it there)
            asm volatile("global_store_dwordx2 %0, %1, off sc0"
                         :: "v"(hd), "v"(qv) : "memory");
            // safety mirror: agent scope (L3), consumed only by fallback path
            __hip_atomic_store(hws + 65536 + poff, qv, __ATOMIC_RELAXED,
                               __HIP_MEMORY_SCOPE_AGENT);
            if (t == 1023) {
                size_t ob = (size_t)(g * 8 + erow) * 512 + c * 16 + 2 * ep;
                out[ob]     = hn0;
                out[ob + 1] = hn1;
            }
        }

        // ---- x-GEMM tail for t+1: xf in flight/regs, B from LDS ----
        float4v ax = {0.f, 0.f, 0.f, 0.f};
#pragma unroll
        for (int kk = 0; kk < 16; kk++) {
            half8 b = *(const half8*)&Xls[w * 16 + l15][kk * 32 + quad * 8];
            ax = __builtin_amdgcn_mfma_f32_16x16x32_f16(xf[kk], b, ax, 0, 0, 0);
        }
        accx = ax;
    }
}

// ------------------------------- launcher ----------------------------------
extern "C" void kernel_launch(void* const* d_in, const int* in_sizes, int n_in,
                              void* d_out, int out_size, void* d_ws, size_t ws_size,
                              hipStream_t stream) {
    const float* X   = (const float*)d_in[0];
    const float* Whf = (const float*)d_in[1];  const float* bhf = (const float*)d_in[2];
    const float* Wxf = (const float*)d_in[3];  const float* bxf = (const float*)d_in[4];
    const float* Whi = (const float*)d_in[5];  const float* bhi = (const float*)d_in[6];
    const float* Wxi = (const float*)d_in[7];  const float* bxi = (const float*)d_in[8];
    const float* Whg = (const float*)d_in[9];  const float* bhg = (const float*)d_in[10];
    const float* Wxg = (const float*)d_in[11]; const float* bxg = (const float*)d_in[12];
    const float* Who = (const float*)d_in[13]; const float* bho = (const float*)d_in[14];
    const float* Wxo = (const float*)d_in[15]; const float* bxo = (const float*)d_in[16];

    // ws: [0,256K) fast tagged h | [256K,+32) XCD slot ctrs | [512K,768K) agent
    // mirror | [1MB,65MB) XH fp16
    if (ws_size < (size_t)68157440) return;  // need 65 MiB

    char* ws = (char*)d_ws;
    unsigned long long* hws = (unsigned long long*)ws;
    _Float16*           XH  = (_Float16*)(ws + (1 << 20));
    (void)in_sizes; (void)n_in; (void)out_size;

    hipMemsetAsync(d_ws, 0, 786432, stream);   // fast buf + ctrs + mirror
    xcvt<<<16384, 256, 0, stream>>>(X, XH);
    lstm_rec<<<256, 256, 0, stream>>>(Whf, Whi, Whg, Who, Wxf, Wxi, Wxg, Wxo,
                                      bxf, bxi, bxg, bxo, bhf, bhi, bhg, bho,
                                      XH, hws, (float*)d_out);
}

// Round 4
// 5662.389 us; speedup vs baseline: 1.4119x; 1.4119x over previous
//
#include <hip/hip_runtime.h>
#include <cstdint>
#include <cstddef>

// ---------------------------------------------------------------------------
// LSTM  B=64, T=1024, D=H=512.
//   * xcvt: x_seq fp32 -> fp16 in ws (one-time).
//   * lstm_rec: persistent, 256 WGs = 8 batch-groups x 32 column-groups,
//     batch-group == physical XCD (runtime XCC_ID + slot counter).
//     Wh & Wx slices LDS-resident fp16 (140 KB, 1 WG/CU).
//   R7: FLAG-CERTIFIED EXCHANGE (fixes R6's poll-payload pathology).
//     R6 evidence: FETCH 247->130 MB proves on-die exchange works, but
//     16KB-per-retry payload polling saturated the XCD L2 (dur 5.4->8.0ms,
//     VALUBusy 2x). R7 never spins on payload:
//       * producer: 512B raw-fp16 payload stores -> vmcnt(0) -> ONE u32
//         flag = t+1 (release). Dual-path: sc0 copy (XCD L2) + agent copy
//         at disjoint addresses (L3) — whichever visibility works carries.
//       * consumer: spins on 32 flags = 2 cache lines (8x16B replicated
//         across the wave, s_sleep(1) backoff); every 4th miss checks the
//         agent mirror (anti-deadlock). On match: ONE 8KB payload read via
//         the matching path, staged to LDS as raw b128 (no tag unpack).
//       * exact-match flag values + skipping the t=0 poll (h0=0 staged
//         locally) make the protocol self-validating against stale cache
//         state — no cleanse phase needed.
// ---------------------------------------------------------------------------

typedef _Float16 half8  __attribute__((ext_vector_type(8)));
typedef _Float16 half4v __attribute__((ext_vector_type(4)));
typedef float    float4v __attribute__((ext_vector_type(4)));
typedef unsigned uint4v  __attribute__((ext_vector_type(4)));

__device__ __forceinline__ float sigm(float x) { return 1.f / (1.f + __expf(-x)); }
__device__ __forceinline__ float tanh_f(float x) { return 2.f / (1.f + __expf(-2.f * x)) - 1.f; }

// ws byte-offset map (all < 1 MB; XH at 1 MB):
//   fast payload [2][8][8192B]  @ 0        (sc0 / XCD-L2 path)
//   fast flags   [2][8][128B]   @ 131072
//   slot ctrs    [8 u32]        @ 139264
//   slow payload [2][8][8192B]  @ 262144   (agent / L3 path)
//   slow flags   [2][8][128B]   @ 393216
#define FAST_PAY   0
#define FAST_FLag  131072
#define SLOT_CTR   139264
#define SLOW_OFF   262144

// ----------------------------- x fp32 -> fp16 ------------------------------
__global__ __launch_bounds__(256) void xcvt(const float* __restrict__ X,
                                            _Float16* __restrict__ XH) {
    size_t i = ((size_t)blockIdx.x * 256 + threadIdx.x) * 8;
    float4 a = *(const float4*)(X + i);
    float4 b = *(const float4*)(X + i + 4);
    half8 v;
    v[0] = (_Float16)a.x; v[1] = (_Float16)a.y; v[2] = (_Float16)a.z; v[3] = (_Float16)a.w;
    v[4] = (_Float16)b.x; v[5] = (_Float16)b.y; v[6] = (_Float16)b.z; v[7] = (_Float16)b.w;
    *(half8*)(XH + i) = v;
}

// ------------------------------- recurrence --------------------------------
__global__ __launch_bounds__(256, 1) void lstm_rec(
    const float* __restrict__ Whf, const float* __restrict__ Whi,
    const float* __restrict__ Whg, const float* __restrict__ Who,
    const float* __restrict__ Wxf, const float* __restrict__ Wxi,
    const float* __restrict__ Wxg, const float* __restrict__ Wxo,
    const float* __restrict__ bxf, const float* __restrict__ bxi,
    const float* __restrict__ bxg, const float* __restrict__ bxo,
    const float* __restrict__ bhf, const float* __restrict__ bhi,
    const float* __restrict__ bhg, const float* __restrict__ bho,
    const _Float16* __restrict__ XH,   // [64][1024][512] fp16
    char* __restrict__ wsb,            // exchange area (see map above)
    float* __restrict__ out)           // [64][512] fp32
{
    const int tid  = threadIdx.x;
    const int w    = tid >> 6;
    const int lane = tid & 63;
    const int l15  = lane & 15;
    const int quad = lane >> 4;
    const int m    = l15 & 7;

    __shared__ _Float16 Wls[64][520];
    __shared__ _Float16 Xls[64][520];
    __shared__ _Float16 hls[8][520];
    __shared__ float    gs[8][65];
    __shared__ unsigned slot_sh;

    // ---- runtime XCD self-organization: g = physical XCD, c = slot ----
    unsigned xcd;
    asm volatile("s_getreg_b32 %0, hwreg(HW_REG_XCC_ID)" : "=s"(xcd));
    xcd &= 7;
    if (tid == 0) {
        unsigned* ctr = (unsigned*)(wsb + SLOT_CTR);
        slot_sh = __hip_atomic_fetch_add(&ctr[xcd], 1u, __ATOMIC_RELAXED,
                                         __HIP_MEMORY_SCOPE_AGENT);
    }
    __syncthreads();
    const int g = (int)xcd;
    const int c = (int)(slot_sh & 31);

    // ---- one-time: weight slices -> LDS fp16 ----
    const float* WhSeg[4] = {Whf, Whi, Whg, Who};
    const float* WxSeg[4] = {Wxf, Wxi, Wxg, Wxo};
    for (int e = tid * 4; e < 64 * 512; e += 1024) {
        int row = e >> 9, col = e & 511;
        int seg = row >> 4;
        int srow = c * 16 + (row & 15);
        float4 vh = *(const float4*)(WhSeg[seg] + (size_t)srow * 512 + col);
        float4 vx = *(const float4*)(WxSeg[seg] + (size_t)srow * 512 + col);
        half4v th = {(_Float16)vh.x, (_Float16)vh.y, (_Float16)vh.z, (_Float16)vh.w};
        half4v tx = {(_Float16)vx.x, (_Float16)vx.y, (_Float16)vx.z, (_Float16)vx.w};
        *(half4v*)&Wls[row][col] = th;
        *(half4v*)&Xls[row][col] = tx;
    }

    // ---- elementwise role (wave 0): fused biases ----
    const int erow = tid >> 3;
    const int ep   = tid & 7;
    float bs[8] = {0.f};
    if (tid < 64) {
        int u0 = c * 16 + 2 * ep, u1 = u0 + 1;
        bs[0] = bxf[u0] + bhf[u0];  bs[4] = bxf[u1] + bhf[u1];
        bs[1] = bxi[u0] + bhi[u0];  bs[5] = bxi[u1] + bhi[u1];
        bs[2] = bxg[u0] + bhg[u0];  bs[6] = bxg[u1] + bhg[u1];
        bs[3] = bxo[u0] + bho[u0];  bs[7] = bxo[u1] + bho[u1];
    }
    float c0s = 0.f, c1s = 0.f;

    // payload staging role: thread reads 32B of the group's 8KB h payload
    const int crow = tid >> 5;          // 0..7
    const int ccol = (tid & 31) << 4;   // elem offset 0..496

    // h_0 = 0: stage locally, skip the t=0 poll entirely.
    {
        uint4v z = {0u, 0u, 0u, 0u};
        *(uint4v*)&hls[crow][ccol]     = z;
        *(uint4v*)&hls[crow][ccol + 8] = z;
    }
    __syncthreads();

    // ---- x-projection shadow: acc_x for step 0 ----
    const size_t xrow = (size_t)(g * 8 + m) * 1024 * 512 + (size_t)quad * 8;
    half8 xf[16];
#pragma unroll
    for (int kk = 0; kk < 16; kk++) xf[kk] = *(const half8*)(XH + xrow + kk * 32);
    float4v accx = {0.f, 0.f, 0.f, 0.f};
#pragma unroll
    for (int kk = 0; kk < 16; kk++) {
        half8 b = *(const half8*)&Xls[w * 16 + l15][kk * 32 + quad * 8];
        accx = __builtin_amdgcn_mfma_f32_16x16x32_f16(xf[kk], b, accx, 0, 0, 0);
    }

    for (int t = 0; t < 1024; t++) {
        // ---- flag spin + single payload read (t=0: hls pre-staged) ----
        if (t > 0) {
            const unsigned tv = (unsigned)t;
            const char* fb = wsb + FAST_FLag + (size_t)(t & 1) * 1024
                           + g * 128 + ((lane & 7) << 4);
            const unsigned* sb = (const unsigned*)(fb + SLOW_OFF);
            bool slow = false;
            int miss = 0;
            for (;;) {
                uint4v fv;
                asm volatile("global_load_dwordx4 %0, %1, off sc0\n\t"
                             "s_waitcnt vmcnt(0)"
                             : "=&v"(fv) : "v"(fb) : "memory");
                if (__all(fv[0] == tv && fv[1] == tv &&
                          fv[2] == tv && fv[3] == tv)) break;
                if (((++miss) & 3) == 0) {   // anti-deadlock: agent mirror
                    unsigned s0 = __hip_atomic_load(sb + 0, __ATOMIC_RELAXED,
                                                    __HIP_MEMORY_SCOPE_AGENT);
                    unsigned s1 = __hip_atomic_load(sb + 1, __ATOMIC_RELAXED,
                                                    __HIP_MEMORY_SCOPE_AGENT);
                    unsigned s2 = __hip_atomic_load(sb + 2, __ATOMIC_RELAXED,
                                                    __HIP_MEMORY_SCOPE_AGENT);
                    unsigned s3 = __hip_atomic_load(sb + 3, __ATOMIC_RELAXED,
                                                    __HIP_MEMORY_SCOPE_AGENT);
                    if (__all(s0 == tv && s1 == tv && s2 == tv && s3 == tv)) {
                        slow = true; break;
                    }
                }
                __builtin_amdgcn_s_sleep(1);
            }
            const size_t poff = (size_t)(t & 1) * 65536 + (size_t)g * 8192
                              + (size_t)tid * 32;
            uint4v p0, p1;
            if (!slow) {
                const char* pp = wsb + poff;
                asm volatile("global_load_dwordx4 %0, %2, off sc0\n\t"
                             "global_load_dwordx4 %1, %2, off offset:16 sc0\n\t"
                             "s_waitcnt vmcnt(0)"
                             : "=&v"(p0), "=&v"(p1) : "v"(pp) : "memory");
            } else {
                const unsigned long long* pp =
                    (const unsigned long long*)(wsb + SLOW_OFF + poff);
                unsigned long long q0 = __hip_atomic_load(pp + 0, __ATOMIC_RELAXED,
                                                          __HIP_MEMORY_SCOPE_AGENT);
                unsigned long long q1 = __hip_atomic_load(pp + 1, __ATOMIC_RELAXED,
                                                          __HIP_MEMORY_SCOPE_AGENT);
                unsigned long long q2 = __hip_atomic_load(pp + 2, __ATOMIC_RELAXED,
                                                          __HIP_MEMORY_SCOPE_AGENT);
                unsigned long long q3 = __hip_atomic_load(pp + 3, __ATOMIC_RELAXED,
                                                          __HIP_MEMORY_SCOPE_AGENT);
                p0[0] = (unsigned)q0; p0[1] = (unsigned)(q0 >> 32);
                p0[2] = (unsigned)q1; p0[3] = (unsigned)(q1 >> 32);
                p1[0] = (unsigned)q2; p1[1] = (unsigned)(q2 >> 32);
                p1[2] = (unsigned)q3; p1[3] = (unsigned)(q3 >> 32);
            }
            *(uint4v*)&hls[crow][ccol]     = p0;
            *(uint4v*)&hls[crow][ccol + 8] = p1;
        }

        // ---- issue x loads for t+1; ride across the raw barriers ----
        {
            int tn = (t < 1023) ? (t + 1) : 0;
            const _Float16* xp = XH + xrow + (size_t)tn * 512;
#pragma unroll
            for (int kk = 0; kk < 16; kk++) xf[kk] = *(const half8*)(xp + kk * 32);
        }

        // barrier 1: hls staged (ds ops drained; vmcnt NOT drained)
        asm volatile("s_waitcnt lgkmcnt(0)" ::: "memory");
        __builtin_amdgcn_s_barrier();
        __builtin_amdgcn_sched_barrier(0);

        // ---- h-GEMM: acc = acc_x + h_t @ Wh_slice^T ----
        float4v acca = accx;
        float4v accb = {0.f, 0.f, 0.f, 0.f};
#pragma unroll
        for (int kk = 0; kk < 16; kk += 2) {
            half8 a0 = *(const half8*)&hls[m][kk * 32 + quad * 8];
            half8 a1 = *(const half8*)&hls[m][(kk + 1) * 32 + quad * 8];
            half8 b0 = *(const half8*)&Wls[w * 16 + l15][kk * 32 + quad * 8];
            half8 b1 = *(const half8*)&Wls[w * 16 + l15][(kk + 1) * 32 + quad * 8];
            acca = __builtin_amdgcn_mfma_f32_16x16x32_f16(a0, b0, acca, 0, 0, 0);
            accb = __builtin_amdgcn_mfma_f32_16x16x32_f16(a1, b1, accb, 0, 0, 0);
        }

        if (quad < 2) {
#pragma unroll
            for (int r = 0; r < 4; r++)
                gs[quad * 4 + r][w * 16 + l15] = acca[r] + accb[r];
        }
        // barrier 2: gs ready
        asm volatile("s_waitcnt lgkmcnt(0)" ::: "memory");
        __builtin_amdgcn_s_barrier();
        __builtin_amdgcn_sched_barrier(0);

        // ---- elementwise LSTM update + dual-path publish (wave 0 only) ----
        if (tid < 64) {
            float pf0 = gs[erow][2 * ep]      + bs[0];
            float pi0 = gs[erow][2 * ep + 16] + bs[1];
            float pg0 = gs[erow][2 * ep + 32] + bs[2];
            float po0 = gs[erow][2 * ep + 48] + bs[3];
            float pf1 = gs[erow][2 * ep + 1]  + bs[4];
            float pi1 = gs[erow][2 * ep + 17] + bs[5];
            float pg1 = gs[erow][2 * ep + 33] + bs[6];
            float po1 = gs[erow][2 * ep + 49] + bs[7];
            c0s = sigm(pf0) * c0s + sigm(pi0) * tanh_f(pg0);
            c1s = sigm(pf1) * c1s + sigm(pi1) * tanh_f(pg1);
            float hn0 = sigm(po0) * tanh_f(c0s);
            float hn1 = sigm(po1) * tanh_f(c1s);
            union { _Float16 f; unsigned short u; } cv0, cv1;
            cv0.f = (_Float16)hn0; cv1.f = (_Float16)hn1;
            unsigned pv = (unsigned)cv0.u | ((unsigned)cv1.u << 16);
            size_t poff = (size_t)((t + 1) & 1) * 65536 + (size_t)g * 8192
                        + (size_t)erow * 1024 + (size_t)(c * 16 + 2 * ep) * 2;
            char* fp = wsb + poff;
            // payload: fast (sc0 -> XCD L2) + slow (agent -> L3), disjoint addrs
            asm volatile("global_store_dword %0, %1, off sc0"
                         :: "v"(fp), "v"(pv) : "memory");
            __hip_atomic_store((unsigned*)(fp + SLOW_OFF), pv, __ATOMIC_RELAXED,
                               __HIP_MEMORY_SCOPE_AGENT);
            // release: payload committed before flag becomes visible
            asm volatile("s_waitcnt vmcnt(0)" ::: "memory");
            if (tid == 0) {
                unsigned fvv = (unsigned)(t + 1);
                char* ff = wsb + FAST_FLag + (size_t)((t + 1) & 1) * 1024
                         + g * 128 + c * 4;
                asm volatile("global_store_dword %0, %1, off sc0"
                             :: "v"(ff), "v"(fvv) : "memory");
                __hip_atomic_store((unsigned*)(ff + SLOW_OFF), fvv,
                                   __ATOMIC_RELAXED, __HIP_MEMORY_SCOPE_AGENT);
            }
            if (t == 1023) {
                size_t ob = (size_t)(g * 8 + erow) * 512 + c * 16 + 2 * ep;
                out[ob]     = hn0;
                out[ob + 1] = hn1;
            }
        }

        // ---- x-GEMM tail for t+1: xf in flight/regs, B from LDS ----
        float4v ax = {0.f, 0.f, 0.f, 0.f};
#pragma unroll
        for (int kk = 0; kk < 16; kk++) {
            half8 b = *(const half8*)&Xls[w * 16 + l15][kk * 32 + quad * 8];
            ax = __builtin_amdgcn_mfma_f32_16x16x32_f16(xf[kk], b, ax, 0, 0, 0);
        }
        accx = ax;
    }
}

// ------------------------------- launcher ----------------------------------
extern "C" void kernel_launch(void* const* d_in, const int* in_sizes, int n_in,
                              void* d_out, int out_size, void* d_ws, size_t ws_size,
                              hipStream_t stream) {
    const float* X   = (const float*)d_in[0];
    const float* Whf = (const float*)d_in[1];  const float* bhf = (const float*)d_in[2];
    const float* Wxf = (const float*)d_in[3];  const float* bxf = (const float*)d_in[4];
    const float* Whi = (const float*)d_in[5];  const float* bhi = (const float*)d_in[6];
    const float* Wxi = (const float*)d_in[7];  const float* bxi = (const float*)d_in[8];
    const float* Whg = (const float*)d_in[9];  const float* bhg = (const float*)d_in[10];
    const float* Wxg = (const float*)d_in[11]; const float* bxg = (const float*)d_in[12];
    const float* Who = (const float*)d_in[13]; const float* bho = (const float*)d_in[14];
    const float* Wxo = (const float*)d_in[15]; const float* bxo = (const float*)d_in[16];

    if (ws_size < (size_t)68157440) return;  // need 65 MiB

    char* ws = (char*)d_ws;
    _Float16* XH = (_Float16*)(ws + (1 << 20));
    (void)in_sizes; (void)n_in; (void)out_size;

    hipMemsetAsync(d_ws, 0, 786432, stream);   // payloads + flags + ctrs
    xcvt<<<16384, 256, 0, stream>>>(X, XH);
    lstm_rec<<<256, 256, 0, stream>>>(Whf, Whi, Whg, Who, Wxf, Wxi, Wxg, Wxo,
                                      bxf, bxi, bxg, bxo, bhf, bhi, bhg, bho,
                                      XH, ws, (float*)d_out);
}